// Round 5
// baseline (42.288 us; speedup 1.0000x reference)
//
#include <hip/hip_runtime.h>
#include <math.h>

#define BSZ 32
#define NPT 8192
#define XB  8          // x-blocks per b1
#define PPT 4          // points per thread (256 thr * 8 blk * 4 = 8192)
#define G   4          // b2-groups (each covers BSZ/G = 8 b2 values)
#define B2P (BSZ / G)  // b2 per group

// out layout: [loss, recall, re_mean, te_mean, rmse_mean]
// d_out is zeroed by a 20-byte memsetAsync each call; all blocks atomicAdd
// pre-scaled contributions. No workspace accumulators needed.

__global__ __launch_bounds__(256) void fused_kernel(
    const float* __restrict__ trans,
    const float* __restrict__ gt_trans,
    const float* __restrict__ src,
    const float* __restrict__ tgt,
    const float* __restrict__ probs,
    float* __restrict__ out)
{
    const int xb  = blockIdx.x;
    const int b1  = blockIdx.y;
    const int g   = blockIdx.z;
    const int tid = threadIdx.x;
    const int n0  = (xb * 256 + tid) * PPT;   // first of 4 points

    // ---- has_inlier(b1): early-exit block-wide any (expected 1 iteration) ----
    const float* prow = probs + (size_t)b1 * NPT;
    int inl = 0;
    for (int base = 0; base < NPT; base += 256 * 4) {
        const float4 pv = *(const float4*)(prow + base + tid * 4);
        const int f = (pv.x > 0.0f) | (pv.y > 0.0f) | (pv.z > 0.0f) | (pv.w > 0.0f);
        if (__syncthreads_or(f)) { inl = 1; break; }
    }

    // R, t for b1 (block-uniform -> SGPRs)
    const float* T = trans + b1 * 16;
    const float r00 = T[0], r01 = T[1], r02 = T[2],  t0 = T[3];
    const float r10 = T[4], r11 = T[5], r12 = T[6],  t1 = T[7];
    const float r20 = T[8], r21 = T[9], r22 = T[10], t2 = T[11];

    // 4 points = 48B = 3 aligned float4 loads
    const float4* sp = (const float4*)(src + ((size_t)b1 * NPT + n0) * 3);
    const float4 sA = sp[0], sB = sp[1], sC = sp[2];
    const float px[4] = {sA.x, sA.w, sB.z, sC.y};
    const float py[4] = {sA.y, sB.x, sB.w, sC.z};
    const float pz[4] = {sA.z, sB.y, sC.x, sC.w};
    float wx[4], wy[4], wz[4];
    #pragma unroll
    for (int i = 0; i < 4; ++i) {
        wx[i] = r00 * px[i] + r01 * py[i] + r02 * pz[i] + t0;
        wy[i] = r10 * px[i] + r11 * py[i] + r12 * pz[i] + t1;
        wz[i] = r20 * px[i] + r21 * py[i] + r22 * pz[i] + t2;
    }

    float acc_sq = 0.0f, acc_rsq = 0.0f;
    #pragma unroll
    for (int k = 0; k < B2P; ++k) {
        const int b2 = g * B2P + k;
        const float4* gp = (const float4*)(tgt + ((size_t)b2 * NPT + n0) * 3);
        const float4 gA = gp[0], gB = gp[1], gC = gp[2];
        const float gx[4] = {gA.x, gA.w, gB.z, gC.y};
        const float gy[4] = {gA.y, gB.x, gB.w, gC.z};
        const float gz[4] = {gA.z, gB.y, gC.x, gC.w};
        #pragma unroll
        for (int i = 0; i < 4; ++i) {
            const float dx = wx[i] - gx[i];
            const float dy = wy[i] - gy[i];
            const float dz = wz[i] - gz[i];
            const float sq = dx * dx + dy * dy + dz * dz;
            acc_sq  += sq;
            acc_rsq += __builtin_amdgcn_sqrtf(sq);
        }
    }

    // wave reduce (64 lanes)
    #pragma unroll
    for (int off = 32; off > 0; off >>= 1) {
        acc_sq  += __shfl_down(acc_sq, off);
        acc_rsq += __shfl_down(acc_rsq, off);
    }

    __shared__ float s_sq[4], s_rsq[4];
    const int wv = tid >> 6;
    if ((tid & 63) == 0) { s_sq[wv] = acc_sq; s_rsq[wv] = acc_rsq; }
    __syncthreads();

    if (tid == 0) {
        const float bsum = s_sq[0] + s_sq[1] + s_sq[2] + s_sq[3];
        const float brs  = s_rsq[0] + s_rsq[1] + s_rsq[2] + s_rsq[3];
        // scale: mean over (BSZ*NPT) then mean over BSZ
        const float scale = 1.0f / ((float)BSZ * (float)NPT * (float)BSZ);
        atomicAdd(&out[0], inl ? bsum * scale : 0.0f);
        atomicAdd(&out[4], brs * scale);

        if (xb == 0 && g == 0) {
            // per-b1 re/te/recall contributions (32 blocks total do this)
            const float* Gt = gt_trans + b1 * 16;
            float tr = 0.0f;
            #pragma unroll
            for (int i = 0; i < 3; ++i)
                #pragma unroll
                for (int j = 0; j < 3; ++j)
                    tr += T[i * 4 + j] * Gt[i * 4 + j];
            float c = (tr - 1.0f) * 0.5f;
            c = fminf(1.0f, fmaxf(-1.0f, c));
            const float re = acosf(c) * 57.29577951308232f;

            const float dx = T[3] - Gt[3];
            const float dy = T[7] - Gt[7];
            const float dz = T[11] - Gt[11];
            const float te = sqrtf(dx * dx + dy * dy + dz * dz) * 100.0f;

            const float recall = ((te < 30.0f) && (re < 15.0f)) ? (100.0f / (float)BSZ) : 0.0f;
            atomicAdd(&out[1], recall);
            atomicAdd(&out[2], re * (1.0f / (float)BSZ));
            atomicAdd(&out[3], te * (1.0f / (float)BSZ));
        }
    }
}

extern "C" void kernel_launch(void* const* d_in, const int* in_sizes, int n_in,
                              void* d_out, int out_size, void* d_ws, size_t ws_size,
                              hipStream_t stream) {
    const float* trans    = (const float*)d_in[0];
    const float* gt_trans = (const float*)d_in[1];
    const float* src      = (const float*)d_in[2];
    const float* tgt      = (const float*)d_in[3];
    const float* probs    = (const float*)d_in[4];
    float* out = (float*)d_out;

    // zero the 5 output accumulators (harness poisons but does not re-zero)
    hipMemsetAsync(d_out, 0, 5 * sizeof(float), stream);

    dim3 grid(XB, BSZ, G);
    fused_kernel<<<grid, 256, 0, stream>>>(trans, gt_trans, src, tgt, probs, out);
}

// Round 6
// 13.330 us; speedup vs baseline: 3.1723x; 3.1723x over previous
//
#include <hip/hip_runtime.h>
#include <math.h>

#define BSZ 32
#define NPT 8192
#define XB  8          // x-blocks per b1
#define PPT 4          // points per thread (256 thr * 8 blk * 4 = 8192)
#define G   8          // b2-groups (each covers BSZ/G = 4 b2 values)
#define B2P (BSZ / G)  // b2 per group

// ws layout (floats):
// [0    .. 2047]  sq  partials  [(b1*XB + xb)*G + g]  (64 contiguous per b1)
// [2048 .. 4095]  rsq partials  (same indexing)
// [4096 .. 4351]  inlier partials [b1*XB + xb]  (g==0 blocks)
// All slots written unconditionally every call -> no zeroing needed.

__global__ __launch_bounds__(256) void fused_kernel(
    const float* __restrict__ trans,
    const float* __restrict__ src,
    const float* __restrict__ tgt,
    const float* __restrict__ probs,
    float* __restrict__ ws)
{
    const int xb  = blockIdx.x;
    const int b1  = blockIdx.y;
    const int g   = blockIdx.z;
    const int tid = threadIdx.x;
    const int n0  = (xb * 256 + tid) * PPT;   // first of 4 points

    // R, t for b1 (block-uniform -> SGPRs)
    const float* T = trans + b1 * 16;
    const float r00 = T[0], r01 = T[1], r02 = T[2],  t0 = T[3];
    const float r10 = T[4], r11 = T[5], r12 = T[6],  t1 = T[7];
    const float r20 = T[8], r21 = T[9], r22 = T[10], t2 = T[11];

    // 4 points = 48B = 3 aligned float4 loads
    const float4* sp = (const float4*)(src + ((size_t)b1 * NPT + n0) * 3);
    const float4 sA = sp[0], sB = sp[1], sC = sp[2];
    const float px[4] = {sA.x, sA.w, sB.z, sC.y};
    const float py[4] = {sA.y, sB.x, sB.w, sC.z};
    const float pz[4] = {sA.z, sB.y, sC.x, sC.w};
    float wx[4], wy[4], wz[4];
    #pragma unroll
    for (int i = 0; i < 4; ++i) {
        wx[i] = r00 * px[i] + r01 * py[i] + r02 * pz[i] + t0;
        wy[i] = r10 * px[i] + r11 * py[i] + r12 * pz[i] + t1;
        wz[i] = r20 * px[i] + r21 * py[i] + r22 * pz[i] + t2;
    }

    float acc_sq = 0.0f, acc_rsq = 0.0f;
    #pragma unroll
    for (int k = 0; k < B2P; ++k) {
        const int b2 = g * B2P + k;
        const float4* gp = (const float4*)(tgt + ((size_t)b2 * NPT + n0) * 3);
        const float4 gA = gp[0], gB = gp[1], gC = gp[2];
        const float gx[4] = {gA.x, gA.w, gB.z, gC.y};
        const float gy[4] = {gA.y, gB.x, gB.w, gC.z};
        const float gz[4] = {gA.z, gB.y, gC.x, gC.w};
        #pragma unroll
        for (int i = 0; i < 4; ++i) {
            const float dx = wx[i] - gx[i];
            const float dy = wy[i] - gy[i];
            const float dz = wz[i] - gz[i];
            const float sq = dx * dx + dy * dy + dz * dz;
            acc_sq  += sq;
            acc_rsq += __builtin_amdgcn_sqrtf(sq);
        }
    }

    // wave reduce (64 lanes)
    #pragma unroll
    for (int off = 32; off > 0; off >>= 1) {
        acc_sq  += __shfl_down(acc_sq, off);
        acc_rsq += __shfl_down(acc_rsq, off);
    }

    __shared__ float s_sq[4], s_rsq[4];
    __shared__ int   s_f[4];
    const int wv = tid >> 6;

    int anyf = 0;
    if (g == 0) {
        // fused probs scan (only one b2-group needs it)
        const float4 pv = *(const float4*)(probs + (size_t)b1 * NPT + n0);
        const int found = (pv.x > 0.0f) | (pv.y > 0.0f) | (pv.z > 0.0f) | (pv.w > 0.0f);
        anyf = (__ballot(found) != 0ull);
    }

    if ((tid & 63) == 0) { s_sq[wv] = acc_sq; s_rsq[wv] = acc_rsq; s_f[wv] = anyf; }
    __syncthreads();
    if (tid == 0) {
        const int slot = (b1 * XB + xb) * G + g;
        ws[slot]        = s_sq[0] + s_sq[1] + s_sq[2] + s_sq[3];
        ws[2048 + slot] = s_rsq[0] + s_rsq[1] + s_rsq[2] + s_rsq[3];
        if (g == 0)
            ws[4096 + b1 * XB + xb] = (s_f[0] | s_f[1] | s_f[2] | s_f[3]) ? 1.0f : 0.0f;
    }
}

__global__ __launch_bounds__(1024) void final_kernel(
    const float* __restrict__ ws,
    const float* __restrict__ trans,
    const float* __restrict__ gt_trans,
    float* __restrict__ out)
{
    const int tid = threadIdx.x;   // 1024 threads = 16 waves

    __shared__ float s_bsq[BSZ], s_brs[BSZ];
    __shared__ int   s_binl[BSZ];
    if (tid < BSZ) s_binl[tid] = 0;
    __syncthreads();

    // 2048 sq + 2048 rsq partials: thread t handles slots 2t, 2t+1 (float2)
    {
        const float2 a = *(const float2*)(ws + 2 * tid);
        const float2 b = *(const float2*)(ws + 2048 + 2 * tid);
        float asum = a.x + a.y;
        float bsum = b.x + b.y;
        // per-b1 segment = 64 slots = 32 threads after pairing -> half-wave reduce
        #pragma unroll
        for (int off = 16; off > 0; off >>= 1) {
            asum += __shfl_down(asum, off, 32);
            bsum += __shfl_down(bsum, off, 32);
        }
        if ((tid & 31) == 0) {
            const int b1 = tid >> 5;
            s_bsq[b1] = asum;
            s_brs[b1] = bsum;
        }
    }
    // inlier: 256 partials, 8 per b1
    if (tid < 256) {
        if (ws[4096 + tid] > 0.5f) atomicOr(&s_binl[tid >> 3], 1);
    }
    __syncthreads();

    float loss_c = 0.0f, recall_c = 0.0f, re_c = 0.0f, te_c = 0.0f, rmse_c = 0.0f;
    if (tid < BSZ) {
        const float* T  = trans + tid * 16;
        const float* Gt = gt_trans + tid * 16;
        float tr = 0.0f;
        #pragma unroll
        for (int i = 0; i < 3; ++i)
            #pragma unroll
            for (int j = 0; j < 3; ++j)
                tr += T[i * 4 + j] * Gt[i * 4 + j];
        float c = (tr - 1.0f) * 0.5f;
        c = fminf(1.0f, fmaxf(-1.0f, c));
        const float re = acosf(c) * 57.29577951308232f;

        const float dx = T[3] - Gt[3];
        const float dy = T[7] - Gt[7];
        const float dz = T[11] - Gt[11];
        const float te = sqrtf(dx * dx + dy * dy + dz * dz) * 100.0f;

        const float inv = 1.0f / ((float)BSZ * (float)NPT);
        loss_c   = s_binl[tid] ? s_bsq[tid] * inv : 0.0f;
        recall_c = ((te < 30.0f) && (re < 15.0f)) ? 1.0f : 0.0f;
        re_c   = re;
        te_c   = te;
        rmse_c = s_brs[tid] * inv;
    }
    if (tid < 64) {
        #pragma unroll
        for (int off = 16; off > 0; off >>= 1) {
            loss_c   += __shfl_down(loss_c, off, 32);
            recall_c += __shfl_down(recall_c, off, 32);
            re_c     += __shfl_down(re_c, off, 32);
            te_c     += __shfl_down(te_c, off, 32);
            rmse_c   += __shfl_down(rmse_c, off, 32);
        }
        if (tid == 0) {
            out[0] = loss_c / (float)BSZ;
            out[1] = recall_c * 100.0f / (float)BSZ;
            out[2] = re_c / (float)BSZ;
            out[3] = te_c / (float)BSZ;
            out[4] = rmse_c / (float)BSZ;
        }
    }
}

extern "C" void kernel_launch(void* const* d_in, const int* in_sizes, int n_in,
                              void* d_out, int out_size, void* d_ws, size_t ws_size,
                              hipStream_t stream) {
    const float* trans    = (const float*)d_in[0];
    const float* gt_trans = (const float*)d_in[1];
    const float* src      = (const float*)d_in[2];
    const float* tgt      = (const float*)d_in[3];
    const float* probs    = (const float*)d_in[4];
    float* ws  = (float*)d_ws;
    float* out = (float*)d_out;

    dim3 grid(XB, BSZ, G);
    fused_kernel<<<grid, 256, 0, stream>>>(trans, src, tgt, probs, ws);
    final_kernel<<<1, 1024, 0, stream>>>(ws, trans, gt_trans, out);
}

// Round 7
// 12.612 us; speedup vs baseline: 3.3529x; 1.0569x over previous
//
#include <hip/hip_runtime.h>
#include <math.h>

#define BSZ 32
#define NPT 8192
#define XB   8         // x-blocks per b1-pair
#define PPT  4         // points per thread (256 thr * 8 blk * 4 = 8192)
#define G    8         // b2-groups
#define B2P (BSZ / G)  // b2 per group = 4
#define NP  (BSZ / 2)  // b1 pairs = 16

// ws layout (floats):
// [0    .. 2047]  sq  partials  [b1*64 + xb*8 + g]   (64 contiguous per b1)
// [2048 .. 4095]  rsq partials  (same indexing)
// [4096 .. 4351]  inlier partials [b1*XB + xb]  (written by g==0 blocks)
// All slots written unconditionally every call -> no zeroing needed.

__global__ __launch_bounds__(256) void fused_kernel(
    const float* __restrict__ trans,
    const float* __restrict__ src,
    const float* __restrict__ tgt,
    const float* __restrict__ probs,
    float* __restrict__ ws)
{
    const int xb  = blockIdx.x;
    const int p   = blockIdx.y;       // b1 pair index 0..15
    const int g   = blockIdx.z;
    const int tid = threadIdx.x;
    const int b1a = 2 * p;
    const int b1b = 2 * p + 1;
    const int n0  = (xb * 256 + tid) * PPT;

    // R, t for both b1 (block-uniform -> SGPRs)
    const float* Ta = trans + b1a * 16;
    const float a00 = Ta[0], a01 = Ta[1], a02 = Ta[2],  at0 = Ta[3];
    const float a10 = Ta[4], a11 = Ta[5], a12 = Ta[6],  at1 = Ta[7];
    const float a20 = Ta[8], a21 = Ta[9], a22 = Ta[10], at2 = Ta[11];
    const float* Tb = trans + b1b * 16;
    const float b00 = Tb[0], b01 = Tb[1], b02 = Tb[2],  bt0 = Tb[3];
    const float b10 = Tb[4], b11 = Tb[5], b12 = Tb[6],  bt1 = Tb[7];
    const float b20 = Tb[8], b21 = Tb[9], b22 = Tb[10], bt2 = Tb[11];

    float wxA[4], wyA[4], wzA[4], wxB[4], wyB[4], wzB[4];
    {
        const float4* sp = (const float4*)(src + ((size_t)b1a * NPT + n0) * 3);
        const float4 sA = sp[0], sB = sp[1], sC = sp[2];
        const float px[4] = {sA.x, sA.w, sB.z, sC.y};
        const float py[4] = {sA.y, sB.x, sB.w, sC.z};
        const float pz[4] = {sA.z, sB.y, sC.x, sC.w};
        #pragma unroll
        for (int i = 0; i < 4; ++i) {
            wxA[i] = a00 * px[i] + a01 * py[i] + a02 * pz[i] + at0;
            wyA[i] = a10 * px[i] + a11 * py[i] + a12 * pz[i] + at1;
            wzA[i] = a20 * px[i] + a21 * py[i] + a22 * pz[i] + at2;
        }
    }
    {
        const float4* sp = (const float4*)(src + ((size_t)b1b * NPT + n0) * 3);
        const float4 sA = sp[0], sB = sp[1], sC = sp[2];
        const float px[4] = {sA.x, sA.w, sB.z, sC.y};
        const float py[4] = {sA.y, sB.x, sB.w, sC.z};
        const float pz[4] = {sA.z, sB.y, sC.x, sC.w};
        #pragma unroll
        for (int i = 0; i < 4; ++i) {
            wxB[i] = b00 * px[i] + b01 * py[i] + b02 * pz[i] + bt0;
            wyB[i] = b10 * px[i] + b11 * py[i] + b12 * pz[i] + bt1;
            wzB[i] = b20 * px[i] + b21 * py[i] + b22 * pz[i] + bt2;
        }
    }

    float asqA = 0.0f, arsA = 0.0f, asqB = 0.0f, arsB = 0.0f;
    #pragma unroll
    for (int k = 0; k < B2P; ++k) {
        const int b2 = g * B2P + k;
        const float4* gp = (const float4*)(tgt + ((size_t)b2 * NPT + n0) * 3);
        const float4 gA = gp[0], gB = gp[1], gC = gp[2];
        const float gx[4] = {gA.x, gA.w, gB.z, gC.y};
        const float gy[4] = {gA.y, gB.x, gB.w, gC.z};
        const float gz[4] = {gA.z, gB.y, gC.x, gC.w};
        #pragma unroll
        for (int i = 0; i < 4; ++i) {
            {
                const float dx = wxA[i] - gx[i];
                const float dy = wyA[i] - gy[i];
                const float dz = wzA[i] - gz[i];
                const float sq = dx * dx + dy * dy + dz * dz;
                asqA += sq;
                arsA += __builtin_amdgcn_sqrtf(sq);
            }
            {
                const float dx = wxB[i] - gx[i];
                const float dy = wyB[i] - gy[i];
                const float dz = wzB[i] - gz[i];
                const float sq = dx * dx + dy * dy + dz * dz;
                asqB += sq;
                arsB += __builtin_amdgcn_sqrtf(sq);
            }
        }
    }

    // wave reduce (64 lanes)
    #pragma unroll
    for (int off = 32; off > 0; off >>= 1) {
        asqA += __shfl_down(asqA, off);
        arsA += __shfl_down(arsA, off);
        asqB += __shfl_down(asqB, off);
        arsB += __shfl_down(arsB, off);
    }

    __shared__ float s_sqA[4], s_rsA[4], s_sqB[4], s_rsB[4];
    __shared__ int   s_fA[4], s_fB[4];
    const int wv = tid >> 6;

    int anyfA = 0, anyfB = 0;
    if (g == 0) {
        const int off = xb * 1024 + tid * 4;
        const float4 pa = *(const float4*)(probs + (size_t)b1a * NPT + off);
        const float4 pb = *(const float4*)(probs + (size_t)b1b * NPT + off);
        const int fa = (pa.x > 0.0f) | (pa.y > 0.0f) | (pa.z > 0.0f) | (pa.w > 0.0f);
        const int fb = (pb.x > 0.0f) | (pb.y > 0.0f) | (pb.z > 0.0f) | (pb.w > 0.0f);
        anyfA = (__ballot(fa) != 0ull);
        anyfB = (__ballot(fb) != 0ull);
    }

    if ((tid & 63) == 0) {
        s_sqA[wv] = asqA; s_rsA[wv] = arsA;
        s_sqB[wv] = asqB; s_rsB[wv] = arsB;
        s_fA[wv] = anyfA; s_fB[wv] = anyfB;
    }
    __syncthreads();
    if (tid == 0) {
        const int sub = xb * 8 + g;
        ws[b1a * 64 + sub]        = s_sqA[0] + s_sqA[1] + s_sqA[2] + s_sqA[3];
        ws[2048 + b1a * 64 + sub] = s_rsA[0] + s_rsA[1] + s_rsA[2] + s_rsA[3];
        ws[b1b * 64 + sub]        = s_sqB[0] + s_sqB[1] + s_sqB[2] + s_sqB[3];
        ws[2048 + b1b * 64 + sub] = s_rsB[0] + s_rsB[1] + s_rsB[2] + s_rsB[3];
        if (g == 0) {
            ws[4096 + b1a * XB + xb] = (s_fA[0] | s_fA[1] | s_fA[2] | s_fA[3]) ? 1.0f : 0.0f;
            ws[4096 + b1b * XB + xb] = (s_fB[0] | s_fB[1] | s_fB[2] | s_fB[3]) ? 1.0f : 0.0f;
        }
    }
}

__global__ __launch_bounds__(1024) void final_kernel(
    const float* __restrict__ ws,
    const float* __restrict__ trans,
    const float* __restrict__ gt_trans,
    float* __restrict__ out)
{
    const int tid = threadIdx.x;   // 1024 threads = 16 waves

    __shared__ float s_bsq[BSZ], s_brs[BSZ];
    __shared__ int   s_binl[BSZ];
    if (tid < BSZ) s_binl[tid] = 0;
    __syncthreads();

    // 2048 sq + 2048 rsq partials: thread t handles slots 2t, 2t+1 (float2)
    {
        const float2 a = *(const float2*)(ws + 2 * tid);
        const float2 b = *(const float2*)(ws + 2048 + 2 * tid);
        float asum = a.x + a.y;
        float bsum = b.x + b.y;
        // per-b1 segment = 64 slots = 32 threads after pairing -> half-wave reduce
        #pragma unroll
        for (int off = 16; off > 0; off >>= 1) {
            asum += __shfl_down(asum, off, 32);
            bsum += __shfl_down(bsum, off, 32);
        }
        if ((tid & 31) == 0) {
            const int b1 = tid >> 5;
            s_bsq[b1] = asum;
            s_brs[b1] = bsum;
        }
    }
    // inlier: 256 partials, 8 per b1
    if (tid < 256) {
        if (ws[4096 + tid] > 0.5f) atomicOr(&s_binl[tid >> 3], 1);
    }
    __syncthreads();

    float loss_c = 0.0f, recall_c = 0.0f, re_c = 0.0f, te_c = 0.0f, rmse_c = 0.0f;
    if (tid < BSZ) {
        const float* T  = trans + tid * 16;
        const float* Gt = gt_trans + tid * 16;
        float tr = 0.0f;
        #pragma unroll
        for (int i = 0; i < 3; ++i)
            #pragma unroll
            for (int j = 0; j < 3; ++j)
                tr += T[i * 4 + j] * Gt[i * 4 + j];
        float c = (tr - 1.0f) * 0.5f;
        c = fminf(1.0f, fmaxf(-1.0f, c));
        const float re = acosf(c) * 57.29577951308232f;

        const float dx = T[3] - Gt[3];
        const float dy = T[7] - Gt[7];
        const float dz = T[11] - Gt[11];
        const float te = sqrtf(dx * dx + dy * dy + dz * dz) * 100.0f;

        const float inv = 1.0f / ((float)BSZ * (float)NPT);
        loss_c   = s_binl[tid] ? s_bsq[tid] * inv : 0.0f;
        recall_c = ((te < 30.0f) && (re < 15.0f)) ? 1.0f : 0.0f;
        re_c   = re;
        te_c   = te;
        rmse_c = s_brs[tid] * inv;
    }
    if (tid < 64) {
        #pragma unroll
        for (int off = 16; off > 0; off >>= 1) {
            loss_c   += __shfl_down(loss_c, off, 32);
            recall_c += __shfl_down(recall_c, off, 32);
            re_c     += __shfl_down(re_c, off, 32);
            te_c     += __shfl_down(te_c, off, 32);
            rmse_c   += __shfl_down(rmse_c, off, 32);
        }
        if (tid == 0) {
            out[0] = loss_c / (float)BSZ;
            out[1] = recall_c * 100.0f / (float)BSZ;
            out[2] = re_c / (float)BSZ;
            out[3] = te_c / (float)BSZ;
            out[4] = rmse_c / (float)BSZ;
        }
    }
}

extern "C" void kernel_launch(void* const* d_in, const int* in_sizes, int n_in,
                              void* d_out, int out_size, void* d_ws, size_t ws_size,
                              hipStream_t stream) {
    const float* trans    = (const float*)d_in[0];
    const float* gt_trans = (const float*)d_in[1];
    const float* src      = (const float*)d_in[2];
    const float* tgt      = (const float*)d_in[3];
    const float* probs    = (const float*)d_in[4];
    float* ws  = (float*)d_ws;
    float* out = (float*)d_out;

    dim3 grid(XB, NP, G);
    fused_kernel<<<grid, 256, 0, stream>>>(trans, src, tgt, probs, ws);
    final_kernel<<<1, 1024, 0, stream>>>(ws, trans, gt_trans, out);
}

// Round 8
// 12.179 us; speedup vs baseline: 3.4723x; 1.0356x over previous
//
#include <hip/hip_runtime.h>
#include <math.h>

#define BSZ 32
#define NPT 8192
#define XB   8         // x-blocks per b1-pair
#define PPT  4         // points per thread (256 thr * 8 blk * 4 = 8192)
#define G    8         // b2-groups
#define B2P (BSZ / G)  // b2 per group = 4
#define NP  (BSZ / 2)  // b1 pairs = 16

// ws layout (floats):
// [0    .. 2047]  sq  partials  [b1*64 + xb*8 + g]   (64 contiguous per b1)
// [2048 .. 4095]  rsq partials  (same indexing)
// [4096 .. 4351]  inlier partials [b1*XB + xb]  (written by g==0 blocks)
// All slots written unconditionally every call -> no zeroing needed.

// DPP wave64 sum (rocPRIM gfx9 sequence). old=0 + bound_ctrl zero-fill makes
// invalid-source lanes contribute 0. Lane 63 ends with the full 64-lane sum.
template<int CTRL>
__device__ __forceinline__ float dpp_shift_add(float x) {
    union { float f; int i; } u, r;
    u.f = x;
    r.i = __builtin_amdgcn_update_dpp(0, u.i, CTRL, 0xF, 0xF, true);
    return x + r.f;
}
__device__ __forceinline__ float wave64_sum(float x) {
    x = dpp_shift_add<0x111>(x);   // row_shr:1
    x = dpp_shift_add<0x112>(x);   // row_shr:2
    x = dpp_shift_add<0x114>(x);   // row_shr:4
    x = dpp_shift_add<0x118>(x);   // row_shr:8
    x = dpp_shift_add<0x142>(x);   // row_bcast:15
    x = dpp_shift_add<0x143>(x);   // row_bcast:31
    return x;                      // valid in lane 63
}

__global__ __launch_bounds__(256) void fused_kernel(
    const float* __restrict__ trans,
    const float* __restrict__ src,
    const float* __restrict__ tgt,
    const float* __restrict__ probs,
    float* __restrict__ ws)
{
    const int xb  = blockIdx.x;
    const int p   = blockIdx.y;       // b1 pair index 0..15
    const int g   = blockIdx.z;
    const int tid = threadIdx.x;
    const int b1a = 2 * p;
    const int b1b = 2 * p + 1;
    const int n0  = (xb * 256 + tid) * PPT;

    // R, t for both b1 (block-uniform -> SGPRs)
    const float* Ta = trans + b1a * 16;
    const float a00 = Ta[0], a01 = Ta[1], a02 = Ta[2],  at0 = Ta[3];
    const float a10 = Ta[4], a11 = Ta[5], a12 = Ta[6],  at1 = Ta[7];
    const float a20 = Ta[8], a21 = Ta[9], a22 = Ta[10], at2 = Ta[11];
    const float* Tb = trans + b1b * 16;
    const float b00 = Tb[0], b01 = Tb[1], b02 = Tb[2],  bt0 = Tb[3];
    const float b10 = Tb[4], b11 = Tb[5], b12 = Tb[6],  bt1 = Tb[7];
    const float b20 = Tb[8], b21 = Tb[9], b22 = Tb[10], bt2 = Tb[11];

    float wxA[4], wyA[4], wzA[4], wxB[4], wyB[4], wzB[4];
    {
        const float4* sp = (const float4*)(src + ((size_t)b1a * NPT + n0) * 3);
        const float4 sA = sp[0], sB = sp[1], sC = sp[2];
        const float px[4] = {sA.x, sA.w, sB.z, sC.y};
        const float py[4] = {sA.y, sB.x, sB.w, sC.z};
        const float pz[4] = {sA.z, sB.y, sC.x, sC.w};
        #pragma unroll
        for (int i = 0; i < 4; ++i) {
            wxA[i] = a00 * px[i] + a01 * py[i] + a02 * pz[i] + at0;
            wyA[i] = a10 * px[i] + a11 * py[i] + a12 * pz[i] + at1;
            wzA[i] = a20 * px[i] + a21 * py[i] + a22 * pz[i] + at2;
        }
    }
    {
        const float4* sp = (const float4*)(src + ((size_t)b1b * NPT + n0) * 3);
        const float4 sA = sp[0], sB = sp[1], sC = sp[2];
        const float px[4] = {sA.x, sA.w, sB.z, sC.y};
        const float py[4] = {sA.y, sB.x, sB.w, sC.z};
        const float pz[4] = {sA.z, sB.y, sC.x, sC.w};
        #pragma unroll
        for (int i = 0; i < 4; ++i) {
            wxB[i] = b00 * px[i] + b01 * py[i] + b02 * pz[i] + bt0;
            wyB[i] = b10 * px[i] + b11 * py[i] + b12 * pz[i] + bt1;
            wzB[i] = b20 * px[i] + b21 * py[i] + b22 * pz[i] + bt2;
        }
    }

    float asqA = 0.0f, arsA = 0.0f, asqB = 0.0f, arsB = 0.0f;
    #pragma unroll
    for (int k = 0; k < B2P; ++k) {
        const int b2 = g * B2P + k;
        const float4* gp = (const float4*)(tgt + ((size_t)b2 * NPT + n0) * 3);
        const float4 gA = gp[0], gB = gp[1], gC = gp[2];
        const float gx[4] = {gA.x, gA.w, gB.z, gC.y};
        const float gy[4] = {gA.y, gB.x, gB.w, gC.z};
        const float gz[4] = {gA.z, gB.y, gC.x, gC.w};
        #pragma unroll
        for (int i = 0; i < 4; ++i) {
            {
                const float dx = wxA[i] - gx[i];
                const float dy = wyA[i] - gy[i];
                const float dz = wzA[i] - gz[i];
                const float sq = dx * dx + dy * dy + dz * dz;
                asqA += sq;
                arsA += __builtin_amdgcn_sqrtf(sq);
            }
            {
                const float dx = wxB[i] - gx[i];
                const float dy = wyB[i] - gy[i];
                const float dz = wzB[i] - gz[i];
                const float sq = dx * dx + dy * dy + dz * dz;
                asqB += sq;
                arsB += __builtin_amdgcn_sqrtf(sq);
            }
        }
    }

    // wave reduce: DPP (VALU pipe), lane 63 holds each sum
    asqA = wave64_sum(asqA);
    arsA = wave64_sum(arsA);
    asqB = wave64_sum(asqB);
    arsB = wave64_sum(arsB);

    __shared__ float s_sqA[4], s_rsA[4], s_sqB[4], s_rsB[4];
    __shared__ int   s_fA[4], s_fB[4];
    const int wv = tid >> 6;

    int anyfA = 0, anyfB = 0;
    if (g == 0) {
        const int off = xb * 1024 + tid * 4;
        const float4 pa = *(const float4*)(probs + (size_t)b1a * NPT + off);
        const float4 pb = *(const float4*)(probs + (size_t)b1b * NPT + off);
        const int fa = (pa.x > 0.0f) | (pa.y > 0.0f) | (pa.z > 0.0f) | (pa.w > 0.0f);
        const int fb = (pb.x > 0.0f) | (pb.y > 0.0f) | (pb.z > 0.0f) | (pb.w > 0.0f);
        anyfA = (__ballot(fa) != 0ull);
        anyfB = (__ballot(fb) != 0ull);
    }

    if ((tid & 63) == 63) {
        s_sqA[wv] = asqA; s_rsA[wv] = arsA;
        s_sqB[wv] = asqB; s_rsB[wv] = arsB;
        s_fA[wv] = anyfA; s_fB[wv] = anyfB;
    }
    __syncthreads();
    if (tid == 0) {
        const int sub = xb * 8 + g;
        ws[b1a * 64 + sub]        = s_sqA[0] + s_sqA[1] + s_sqA[2] + s_sqA[3];
        ws[2048 + b1a * 64 + sub] = s_rsA[0] + s_rsA[1] + s_rsA[2] + s_rsA[3];
        ws[b1b * 64 + sub]        = s_sqB[0] + s_sqB[1] + s_sqB[2] + s_sqB[3];
        ws[2048 + b1b * 64 + sub] = s_rsB[0] + s_rsB[1] + s_rsB[2] + s_rsB[3];
        if (g == 0) {
            ws[4096 + b1a * XB + xb] = (s_fA[0] | s_fA[1] | s_fA[2] | s_fA[3]) ? 1.0f : 0.0f;
            ws[4096 + b1b * XB + xb] = (s_fB[0] | s_fB[1] | s_fB[2] | s_fB[3]) ? 1.0f : 0.0f;
        }
    }
}

__global__ __launch_bounds__(1024) void final_kernel(
    const float* __restrict__ ws,
    const float* __restrict__ trans,
    const float* __restrict__ gt_trans,
    float* __restrict__ out)
{
    const int tid = threadIdx.x;   // 1024 threads = 16 waves

    __shared__ float s_bsq[BSZ], s_brs[BSZ];
    __shared__ int   s_binl[BSZ];
    if (tid < BSZ) s_binl[tid] = 0;
    __syncthreads();

    // 2048 sq + 2048 rsq partials: thread t handles slots 2t, 2t+1 (float2)
    {
        const float2 a = *(const float2*)(ws + 2 * tid);
        const float2 b = *(const float2*)(ws + 2048 + 2 * tid);
        float asum = a.x + a.y;
        float bsum = b.x + b.y;
        // per-b1 segment = 64 slots = 32 threads after pairing -> half-wave reduce
        #pragma unroll
        for (int off = 16; off > 0; off >>= 1) {
            asum += __shfl_down(asum, off, 32);
            bsum += __shfl_down(bsum, off, 32);
        }
        if ((tid & 31) == 0) {
            const int b1 = tid >> 5;
            s_bsq[b1] = asum;
            s_brs[b1] = bsum;
        }
    }
    // inlier: 256 partials, 8 per b1
    if (tid < 256) {
        if (ws[4096 + tid] > 0.5f) atomicOr(&s_binl[tid >> 3], 1);
    }
    __syncthreads();

    float loss_c = 0.0f, recall_c = 0.0f, re_c = 0.0f, te_c = 0.0f, rmse_c = 0.0f;
    if (tid < BSZ) {
        const float* T  = trans + tid * 16;
        const float* Gt = gt_trans + tid * 16;
        float tr = 0.0f;
        #pragma unroll
        for (int i = 0; i < 3; ++i)
            #pragma unroll
            for (int j = 0; j < 3; ++j)
                tr += T[i * 4 + j] * Gt[i * 4 + j];
        float c = (tr - 1.0f) * 0.5f;
        c = fminf(1.0f, fmaxf(-1.0f, c));
        const float re = acosf(c) * 57.29577951308232f;

        const float dx = T[3] - Gt[3];
        const float dy = T[7] - Gt[7];
        const float dz = T[11] - Gt[11];
        const float te = sqrtf(dx * dx + dy * dy + dz * dz) * 100.0f;

        const float inv = 1.0f / ((float)BSZ * (float)NPT);
        loss_c   = s_binl[tid] ? s_bsq[tid] * inv : 0.0f;
        recall_c = ((te < 30.0f) && (re < 15.0f)) ? 1.0f : 0.0f;
        re_c   = re;
        te_c   = te;
        rmse_c = s_brs[tid] * inv;
    }
    if (tid < 64) {
        #pragma unroll
        for (int off = 16; off > 0; off >>= 1) {
            loss_c   += __shfl_down(loss_c, off, 32);
            recall_c += __shfl_down(recall_c, off, 32);
            re_c     += __shfl_down(re_c, off, 32);
            te_c     += __shfl_down(te_c, off, 32);
            rmse_c   += __shfl_down(rmse_c, off, 32);
        }
        if (tid == 0) {
            out[0] = loss_c / (float)BSZ;
            out[1] = recall_c * 100.0f / (float)BSZ;
            out[2] = re_c / (float)BSZ;
            out[3] = te_c / (float)BSZ;
            out[4] = rmse_c / (float)BSZ;
        }
    }
}

extern "C" void kernel_launch(void* const* d_in, const int* in_sizes, int n_in,
                              void* d_out, int out_size, void* d_ws, size_t ws_size,
                              hipStream_t stream) {
    const float* trans    = (const float*)d_in[0];
    const float* gt_trans = (const float*)d_in[1];
    const float* src      = (const float*)d_in[2];
    const float* tgt      = (const float*)d_in[3];
    const float* probs    = (const float*)d_in[4];
    float* ws  = (float*)d_ws;
    float* out = (float*)d_out;

    dim3 grid(XB, NP, G);
    fused_kernel<<<grid, 256, 0, stream>>>(trans, src, tgt, probs, ws);
    final_kernel<<<1, 1024, 0, stream>>>(ws, trans, gt_trans, out);
}